// Round 1
// baseline (3037.871 us; speedup 1.0000x reference)
//
#include <hip/hip_runtime.h>

#define NN 50000
#define EE 800000
#define DIM 128
#define OUTD 4
#define EPSV 1e-5f

// ---------------------------------------------------------------------------
// Scatter-add: for each edge e, agg[dst[e]] += feat[src[e]] (128 f32).
// Thread layout: 32 threads per edge, one float4 chunk each.
// Optionally counts degree (layer 0 only).
// ---------------------------------------------------------------------------
__global__ __launch_bounds__(256) void scatter_kernel(
    const float* __restrict__ feat,
    const int* __restrict__ src,
    const int* __restrict__ dst,
    float* __restrict__ agg,
    float* __restrict__ deg,
    int do_deg)
{
    long gid = (long)blockIdx.x * blockDim.x + threadIdx.x;
    if (gid >= (long)EE * 32) return;
    int e = (int)(gid >> 5);
    int c = (int)(gid & 31);
    int s = src[e];
    int d = dst[e];
    float4 v = ((const float4*)(feat + (size_t)s * DIM))[c];
    float* ap = agg + (size_t)d * DIM + c * 4;
    atomicAdd(ap + 0, v.x);
    atomicAdd(ap + 1, v.y);
    atomicAdd(ap + 2, v.z);
    atomicAdd(ap + 3, v.w);
    if (do_deg && c == 0) atomicAdd(deg + d, 1.0f);
}

__global__ __launch_bounds__(256) void deginv_kernel(float* __restrict__ deg)
{
    int n = blockIdx.x * blockDim.x + threadIdx.x;
    if (n < NN) deg[n] = 1.0f / fmaxf(deg[n], 1.0f);
}

// ---------------------------------------------------------------------------
// Fused: out_pre = (agg*deg_inv) @ Wl + bl + xin @ Wr ; LN ; ReLU
// DO_HEAD=0: write h [N,128].  DO_HEAD=1: out = h2 @ Wh + bh -> [N,4].
// Block: 256 threads, 32 nodes. Each thread: column j = tid&127,
// nodes (tid>>7)*16 .. +15, 16 accumulators.
// ---------------------------------------------------------------------------
template <int DO_HEAD>
__global__ __launch_bounds__(256) void sage_gemm_kernel(
    const float* __restrict__ agg,
    const float* __restrict__ deg_inv,
    const float* __restrict__ xin,
    const float* __restrict__ Wl, const float* __restrict__ bl,
    const float* __restrict__ Wr,
    const float* __restrict__ g, const float* __restrict__ beta,
    const float* __restrict__ Wh, const float* __restrict__ bh,
    float* __restrict__ out)
{
    __shared__ float aT[32][DIM];
    __shared__ float xT[32][DIM];
    __shared__ float oT[32][DIM + 1];
    __shared__ float mu_s[32], ri_s[32];

    int tid = threadIdx.x;
    int base = blockIdx.x * 32;

    // Load tiles (agg scaled by deg_inv) - 1024 float4 per tile, 4 per thread.
    #pragma unroll
    for (int i = 0; i < 4; i++) {
        int idx = tid + i * 256;
        int n = idx >> 5;
        int c = idx & 31;
        int node = base + n;
        float4 av = make_float4(0.f, 0.f, 0.f, 0.f);
        float4 xv = av;
        if (node < NN) {
            av = ((const float4*)(agg + (size_t)node * DIM))[c];
            float di = deg_inv[node];
            av.x *= di; av.y *= di; av.z *= di; av.w *= di;
            xv = ((const float4*)(xin + (size_t)node * DIM))[c];
        }
        ((float4*)&aT[n][0])[c] = av;
        ((float4*)&xT[n][0])[c] = xv;
    }
    __syncthreads();

    int j = tid & 127;
    int half = tid >> 7;
    float acc[16];
    #pragma unroll
    for (int i = 0; i < 16; i++) acc[i] = 0.f;

    for (int k = 0; k < DIM; k += 4) {
        float wl0 = Wl[(k + 0) * DIM + j];
        float wl1 = Wl[(k + 1) * DIM + j];
        float wl2 = Wl[(k + 2) * DIM + j];
        float wl3 = Wl[(k + 3) * DIM + j];
        float wr0 = Wr[(k + 0) * DIM + j];
        float wr1 = Wr[(k + 1) * DIM + j];
        float wr2 = Wr[(k + 2) * DIM + j];
        float wr3 = Wr[(k + 3) * DIM + j];
        #pragma unroll
        for (int i = 0; i < 16; i++) {
            int n = half * 16 + i;
            float4 a4 = *(const float4*)&aT[n][k];
            float4 x4 = *(const float4*)&xT[n][k];
            acc[i] += a4.x * wl0 + a4.y * wl1 + a4.z * wl2 + a4.w * wl3
                    + x4.x * wr0 + x4.y * wr1 + x4.z * wr2 + x4.w * wr3;
        }
    }

    float bj = bl[j];
    #pragma unroll
    for (int i = 0; i < 16; i++) {
        int n = half * 16 + i;
        oT[n][j] = acc[i] + bj;
    }
    __syncthreads();

    // LayerNorm stats: 8 threads per node.
    {
        int n = tid >> 3, l = tid & 7;
        float s = 0.f, s2 = 0.f;
        #pragma unroll
        for (int kk = 0; kk < 16; kk++) {
            float v = oT[n][l * 16 + kk];
            s += v;
            s2 += v * v;
        }
        #pragma unroll
        for (int off = 4; off; off >>= 1) {
            s  += __shfl_down(s, off, 8);
            s2 += __shfl_down(s2, off, 8);
        }
        if (l == 0) {
            float mu = s * (1.0f / DIM);
            float var = s2 * (1.0f / DIM) - mu * mu;
            mu_s[n] = mu;
            ri_s[n] = rsqrtf(fmaxf(var, 0.f) + EPSV);
        }
    }
    __syncthreads();

    if (!DO_HEAD) {
        #pragma unroll
        for (int i = 0; i < 16; i++) {
            int idx = tid + i * 256;
            int n = idx >> 7;
            int k = idx & 127;
            int node = base + n;
            if (node < NN) {
                float v = (oT[n][k] - mu_s[n]) * ri_s[n] * g[k] + beta[k];
                out[(size_t)node * DIM + k] = fmaxf(v, 0.f);
            }
        }
    } else {
        float vals[16];
        #pragma unroll
        for (int i = 0; i < 16; i++) {
            int idx = tid + i * 256;
            int n = idx >> 7;
            int k = idx & 127;
            float v = (oT[n][k] - mu_s[n]) * ri_s[n] * g[k] + beta[k];
            vals[i] = fmaxf(v, 0.f);
        }
        __syncthreads();
        #pragma unroll
        for (int i = 0; i < 16; i++) {
            int idx = tid + i * 256;
            int n = idx >> 7;
            int k = idx & 127;
            oT[n][k] = vals[i];
        }
        __syncthreads();
        if (tid < 128) {
            int n = tid >> 2, o = tid & 3;
            int node = base + n;
            if (node < NN) {
                float s = bh[o];
                for (int k = 0; k < DIM; k++) s += oT[n][k] * Wh[k * OUTD + o];
                out[(size_t)node * OUTD + o] = s;
            }
        }
    }
}

extern "C" void kernel_launch(void* const* d_in, const int* in_sizes, int n_in,
                              void* d_out, int out_size, void* d_ws, size_t ws_size,
                              hipStream_t stream)
{
    const float* x    = (const float*)d_in[0];
    const int*   ei   = (const int*)d_in[1];   // [2, E] int32
    const float* Wl0  = (const float*)d_in[2];
    const float* bl0  = (const float*)d_in[3];
    const float* Wr0  = (const float*)d_in[4];
    const float* Wl1  = (const float*)d_in[5];
    const float* bl1  = (const float*)d_in[6];
    const float* Wr1  = (const float*)d_in[7];
    const float* g0   = (const float*)d_in[8];
    const float* be0  = (const float*)d_in[9];
    const float* g1   = (const float*)d_in[10];
    const float* be1  = (const float*)d_in[11];
    const float* Wh   = (const float*)d_in[12];
    const float* bh   = (const float*)d_in[13];
    float* out = (float*)d_out;

    const int* srcI = ei;
    const int* dstI = ei + EE;

    const size_t AGG_BYTES = (size_t)NN * DIM * sizeof(float);  // 25.6 MB
    float* agg = (float*)d_ws;
    float* h   = (float*)((char*)d_ws + AGG_BYTES);
    float* deg = (float*)((char*)d_ws + 2 * AGG_BYTES);

    hipMemsetAsync(agg, 0, AGG_BYTES, stream);
    hipMemsetAsync(deg, 0, NN * sizeof(float), stream);

    const int SC_THREADS = 256;
    const long sc_total = (long)EE * 32;
    const int sc_blocks = (int)((sc_total + SC_THREADS - 1) / SC_THREADS);

    scatter_kernel<<<sc_blocks, SC_THREADS, 0, stream>>>(x, srcI, dstI, agg, deg, 1);
    deginv_kernel<<<(NN + 255) / 256, 256, 0, stream>>>(deg);

    const int gemm_blocks = (NN + 31) / 32;
    sage_gemm_kernel<0><<<gemm_blocks, 256, 0, stream>>>(
        agg, deg, x, Wl0, bl0, Wr0, g0, be0, nullptr, nullptr, h);

    hipMemsetAsync(agg, 0, AGG_BYTES, stream);
    scatter_kernel<<<sc_blocks, SC_THREADS, 0, stream>>>(h, srcI, dstI, agg, nullptr, 0);

    sage_gemm_kernel<1><<<gemm_blocks, 256, 0, stream>>>(
        agg, deg, h, Wl1, bl1, Wr1, g1, be1, Wh, bh, out);
}

// Round 2
// 813.868 us; speedup vs baseline: 3.7326x; 3.7326x over previous
//
#include <hip/hip_runtime.h>

#define NN 50000
#define EE 800000
#define DIM 128
#define OUTD 4
#define EPSV 1e-5f

// ---------------------------------------------------------------------------
// CSR build step 1: degree histogram (int atomics, cheap).
// ---------------------------------------------------------------------------
__global__ __launch_bounds__(256) void hist_kernel(
    const int* __restrict__ dst, int* __restrict__ cnt)
{
    int e = blockIdx.x * 256 + threadIdx.x;
    if (e < EE) atomicAdd(&cnt[dst[e]], 1);
}

// ---------------------------------------------------------------------------
// CSR build step 2: exclusive prefix scan over 50k degrees, single block of
// 1024 threads (16 waves), next-chunk prefetch to hide load latency.
// rowptr[NN] = EE at the end.
// ---------------------------------------------------------------------------
__global__ __launch_bounds__(1024) void scan_kernel(
    const int* __restrict__ cnt, int* __restrict__ rowptr)
{
    __shared__ int wsum[16];
    __shared__ int carry_s;
    int tid = threadIdx.x;
    int lane = tid & 63, wid = tid >> 6;
    if (tid == 0) carry_s = 0;
    __syncthreads();

    int v_next = (tid < NN) ? cnt[tid] : 0;
    for (int base = 0; base < NN; base += 1024) {
        int v = v_next;
        int nidx = base + 1024 + tid;
        v_next = (nidx < NN) ? cnt[nidx] : 0;

        // inclusive wave scan
        int s = v;
        #pragma unroll
        for (int off = 1; off < 64; off <<= 1) {
            int t = __shfl_up(s, off, 64);
            if (lane >= off) s += t;
        }
        if (lane == 63) wsum[wid] = s;
        __syncthreads();
        if (tid < 16) {
            int w = wsum[tid];
            #pragma unroll
            for (int off = 1; off < 16; off <<= 1) {
                int t = __shfl_up(w, off, 16);
                if (tid >= off) w += t;
            }
            wsum[tid] = w;  // inclusive scan of wave totals
        }
        __syncthreads();
        int idx = base + tid;
        int excl = carry_s + (wid ? wsum[wid - 1] : 0) + (s - v);
        if (idx < NN) rowptr[idx] = excl;
        __syncthreads();
        if (tid == 0) carry_s += wsum[15];
        __syncthreads();
    }
    if (tid == 0) rowptr[NN] = carry_s;
}

// ---------------------------------------------------------------------------
// CSR build step 3: scatter edge source ids into per-dst slots.
// ---------------------------------------------------------------------------
__global__ __launch_bounds__(256) void fill_kernel(
    const int* __restrict__ src, const int* __restrict__ dst,
    const int* __restrict__ rowptr, int* __restrict__ cursor,
    int* __restrict__ col)
{
    int e = blockIdx.x * 256 + threadIdx.x;
    if (e >= EE) return;
    int d = dst[e];
    int pos = rowptr[d] + atomicAdd(&cursor[d], 1);
    col[pos] = src[e];
}

// ---------------------------------------------------------------------------
// Fused: gather-mean(feat over CSR neighbors) -> aT ; self feat -> xT ;
// out_pre = aT @ Wl + bl + xT @ Wr ; LayerNorm ; ReLU ;
// DO_HEAD=0: write h [N,128].  DO_HEAD=1: out = h2 @ Wh + bh -> [N,4].
// Block: 256 threads = 4 waves, 32 nodes. Gather: each wave owns 8 nodes,
// 64 lanes x float2 = one 512B feature row per edge.
// ---------------------------------------------------------------------------
template <int DO_HEAD>
__global__ __launch_bounds__(256) void sage_fused_kernel(
    const float* __restrict__ feat,
    const int* __restrict__ rowptr, const int* __restrict__ col,
    const float* __restrict__ Wl, const float* __restrict__ bl,
    const float* __restrict__ Wr,
    const float* __restrict__ g, const float* __restrict__ beta,
    const float* __restrict__ Wh, const float* __restrict__ bh,
    float* __restrict__ out)
{
    __shared__ float aT[32][DIM];
    __shared__ float xT[32][DIM];
    __shared__ float oT[32][DIM + 1];
    __shared__ float mu_s[32], ri_s[32];

    int tid = threadIdx.x;
    int base = blockIdx.x * 32;

    // Self-feature tile (issue these global loads first).
    #pragma unroll
    for (int i = 0; i < 4; i++) {
        int idx = tid + i * 256;
        int n = idx >> 5;
        int c = idx & 31;
        int node = base + n;
        float4 xv = make_float4(0.f, 0.f, 0.f, 0.f);
        if (node < NN) xv = ((const float4*)(feat + (size_t)node * DIM))[c];
        ((float4*)&xT[n][0])[c] = xv;
    }

    // Gather-mean neighbor features into aT. Wave w owns nodes w*8..w*8+7.
    {
        int lane = tid & 63, w = tid >> 6;
        for (int i = 0; i < 8; i++) {
            int n = w * 8 + i;
            int node = base + n;
            int beg = 0, end = 0;
            if (node < NN) { beg = rowptr[node]; end = rowptr[node + 1]; }
            float2 acc = make_float2(0.f, 0.f);
            for (int e = beg; e < end; e++) {
                int s = col[e];
                float2 v = ((const float2*)(feat + (size_t)s * DIM))[lane];
                acc.x += v.x; acc.y += v.y;
            }
            float di = 1.0f / fmaxf((float)(end - beg), 1.0f);
            ((float2*)&aT[n][0])[lane] = make_float2(acc.x * di, acc.y * di);
        }
    }
    __syncthreads();

    int j = tid & 127;
    int half = tid >> 7;
    float acc[16];
    #pragma unroll
    for (int i = 0; i < 16; i++) acc[i] = 0.f;

    for (int k = 0; k < DIM; k += 4) {
        float wl0 = Wl[(k + 0) * DIM + j];
        float wl1 = Wl[(k + 1) * DIM + j];
        float wl2 = Wl[(k + 2) * DIM + j];
        float wl3 = Wl[(k + 3) * DIM + j];
        float wr0 = Wr[(k + 0) * DIM + j];
        float wr1 = Wr[(k + 1) * DIM + j];
        float wr2 = Wr[(k + 2) * DIM + j];
        float wr3 = Wr[(k + 3) * DIM + j];
        #pragma unroll
        for (int i = 0; i < 16; i++) {
            int n = half * 16 + i;
            float4 a4 = *(const float4*)&aT[n][k];
            float4 x4 = *(const float4*)&xT[n][k];
            acc[i] += a4.x * wl0 + a4.y * wl1 + a4.z * wl2 + a4.w * wl3
                    + x4.x * wr0 + x4.y * wr1 + x4.z * wr2 + x4.w * wr3;
        }
    }

    float bj = bl[j];
    #pragma unroll
    for (int i = 0; i < 16; i++) {
        int n = half * 16 + i;
        oT[n][j] = acc[i] + bj;
    }
    __syncthreads();

    // LayerNorm stats: 8 threads per node.
    {
        int n = tid >> 3, l = tid & 7;
        float s = 0.f, s2 = 0.f;
        #pragma unroll
        for (int kk = 0; kk < 16; kk++) {
            float v = oT[n][l * 16 + kk];
            s += v;
            s2 += v * v;
        }
        #pragma unroll
        for (int off = 4; off; off >>= 1) {
            s  += __shfl_down(s, off, 8);
            s2 += __shfl_down(s2, off, 8);
        }
        if (l == 0) {
            float mu = s * (1.0f / DIM);
            float var = s2 * (1.0f / DIM) - mu * mu;
            mu_s[n] = mu;
            ri_s[n] = rsqrtf(fmaxf(var, 0.f) + EPSV);
        }
    }
    __syncthreads();

    if (!DO_HEAD) {
        #pragma unroll
        for (int i = 0; i < 16; i++) {
            int idx = tid + i * 256;
            int n = idx >> 7;
            int k = idx & 127;
            int node = base + n;
            if (node < NN) {
                float v = (oT[n][k] - mu_s[n]) * ri_s[n] * g[k] + beta[k];
                out[(size_t)node * DIM + k] = fmaxf(v, 0.f);
            }
        }
    } else {
        float vals[16];
        #pragma unroll
        for (int i = 0; i < 16; i++) {
            int idx = tid + i * 256;
            int n = idx >> 7;
            int k = idx & 127;
            float v = (oT[n][k] - mu_s[n]) * ri_s[n] * g[k] + beta[k];
            vals[i] = fmaxf(v, 0.f);
        }
        __syncthreads();
        #pragma unroll
        for (int i = 0; i < 16; i++) {
            int idx = tid + i * 256;
            int n = idx >> 7;
            int k = idx & 127;
            oT[n][k] = vals[i];
        }
        __syncthreads();
        if (tid < 128) {
            int n = tid >> 2, o = tid & 3;
            int node = base + n;
            if (node < NN) {
                float s = bh[o];
                for (int k = 0; k < DIM; k++) s += oT[n][k] * Wh[k * OUTD + o];
                out[(size_t)node * OUTD + o] = s;
            }
        }
    }
}

extern "C" void kernel_launch(void* const* d_in, const int* in_sizes, int n_in,
                              void* d_out, int out_size, void* d_ws, size_t ws_size,
                              hipStream_t stream)
{
    const float* x    = (const float*)d_in[0];
    const int*   ei   = (const int*)d_in[1];   // [2, E] int32
    const float* Wl0  = (const float*)d_in[2];
    const float* bl0  = (const float*)d_in[3];
    const float* Wr0  = (const float*)d_in[4];
    const float* Wl1  = (const float*)d_in[5];
    const float* bl1  = (const float*)d_in[6];
    const float* Wr1  = (const float*)d_in[7];
    const float* g0   = (const float*)d_in[8];
    const float* be0  = (const float*)d_in[9];
    const float* g1   = (const float*)d_in[10];
    const float* be1  = (const float*)d_in[11];
    const float* Wh   = (const float*)d_in[12];
    const float* bh   = (const float*)d_in[13];
    float* out = (float*)d_out;

    const int* srcI = ei;
    const int* dstI = ei + EE;

    // Workspace layout: h [N*128 f32] | rowptr [N+1] | cnt [N] | col [E]
    float* h      = (float*)d_ws;
    int*   rowptr = (int*)((char*)d_ws + (size_t)NN * DIM * sizeof(float));
    int*   cnt    = rowptr + (NN + 1);
    int*   col    = cnt + NN;

    // --- CSR build (per call; edge_index constant but no static guards) ---
    hipMemsetAsync(cnt, 0, NN * sizeof(int), stream);
    hist_kernel<<<(EE + 255) / 256, 256, 0, stream>>>(dstI, cnt);
    scan_kernel<<<1, 1024, 0, stream>>>(cnt, rowptr);
    hipMemsetAsync(cnt, 0, NN * sizeof(int), stream);
    fill_kernel<<<(EE + 255) / 256, 256, 0, stream>>>(srcI, dstI, rowptr, cnt, col);

    // --- two fused SAGE layers ---
    const int gemm_blocks = (NN + 31) / 32;
    sage_fused_kernel<0><<<gemm_blocks, 256, 0, stream>>>(
        x, rowptr, col, Wl0, bl0, Wr0, g0, be0, nullptr, nullptr, h);
    sage_fused_kernel<1><<<gemm_blocks, 256, 0, stream>>>(
        h, rowptr, col, Wl1, bl1, Wr1, g1, be1, Wh, bh, out);
}

// Round 3
// 515.666 us; speedup vs baseline: 5.8912x; 1.5783x over previous
//
#include <hip/hip_runtime.h>

#define NN 50000
#define EE 800000
#define DIM 128
#define OUTD 4
#define EPSV 1e-5f

// ---------------------------------------------------------------------------
// CSR build step 1: degree histogram (int atomics, cheap).
// ---------------------------------------------------------------------------
__global__ __launch_bounds__(256) void hist_kernel(
    const int* __restrict__ dst, int* __restrict__ cnt)
{
    int e = blockIdx.x * 256 + threadIdx.x;
    if (e < EE) atomicAdd(&cnt[dst[e]], 1);
}

// ---------------------------------------------------------------------------
// CSR build step 2: exclusive prefix scan over 50k degrees, single block of
// 1024 threads (16 waves), next-chunk prefetch. rowptr[NN] = EE at the end.
// ---------------------------------------------------------------------------
__global__ __launch_bounds__(1024) void scan_kernel(
    const int* __restrict__ cnt, int* __restrict__ rowptr)
{
    __shared__ int wsum[16];
    __shared__ int carry_s;
    int tid = threadIdx.x;
    int lane = tid & 63, wid = tid >> 6;
    if (tid == 0) carry_s = 0;
    __syncthreads();

    int v_next = (tid < NN) ? cnt[tid] : 0;
    for (int base = 0; base < NN; base += 1024) {
        int v = v_next;
        int nidx = base + 1024 + tid;
        v_next = (nidx < NN) ? cnt[nidx] : 0;

        int s = v;
        #pragma unroll
        for (int off = 1; off < 64; off <<= 1) {
            int t = __shfl_up(s, off, 64);
            if (lane >= off) s += t;
        }
        if (lane == 63) wsum[wid] = s;
        __syncthreads();
        if (tid < 16) {
            int w = wsum[tid];
            #pragma unroll
            for (int off = 1; off < 16; off <<= 1) {
                int t = __shfl_up(w, off, 16);
                if (tid >= off) w += t;
            }
            wsum[tid] = w;
        }
        __syncthreads();
        int idx = base + tid;
        int excl = carry_s + (wid ? wsum[wid - 1] : 0) + (s - v);
        if (idx < NN) rowptr[idx] = excl;
        __syncthreads();
        if (tid == 0) carry_s += wsum[15];
        __syncthreads();
    }
    if (tid == 0) rowptr[NN] = carry_s;
}

// ---------------------------------------------------------------------------
// CSR build step 3: scatter edge source ids into per-dst slots.
// ---------------------------------------------------------------------------
__global__ __launch_bounds__(256) void fill_kernel(
    const int* __restrict__ src, const int* __restrict__ dst,
    const int* __restrict__ rowptr, int* __restrict__ cursor,
    int* __restrict__ col)
{
    int e = blockIdx.x * 256 + threadIdx.x;
    if (e >= EE) return;
    int d = dst[e];
    int pos = rowptr[d] + atomicAdd(&cursor[d], 1);
    col[pos] = src[e];
}

// ---------------------------------------------------------------------------
// Fused layer. Gather: wave w owns 8 nodes; per node, each half-wave (32
// lanes x float4 = 512B row) takes one edge parity, unrolled x2 => 4 rows
// in flight. LDS: oT overlays aT (stride 132) to fit 4 blocks/CU.
// ---------------------------------------------------------------------------
#define OTS 132   // oT stride (floats): 132 => bank = 4n+16l+kk, <=4-way

template <int DO_HEAD>
__global__ __launch_bounds__(256) void sage_fused_kernel(
    const float* __restrict__ feat,
    const int* __restrict__ rowptr, const int* __restrict__ col,
    const float* __restrict__ Wl, const float* __restrict__ bl,
    const float* __restrict__ Wr,
    const float* __restrict__ g, const float* __restrict__ beta,
    const float* __restrict__ Wh, const float* __restrict__ bh,
    float* __restrict__ out)
{
    __shared__ __align__(16) float sAO[32 * OTS];   // aT (stride 128) then oT (stride 132)
    __shared__ __align__(16) float xT[32][DIM];
    __shared__ float mu_s[32], ri_s[32];
    #define AT4(n) ((float4*)&sAO[(n) * DIM])
    #define OT(n, k) sAO[(n) * OTS + (k)]

    int tid = threadIdx.x;
    int base = blockIdx.x * 32;

    // Self-feature tile.
    #pragma unroll
    for (int i = 0; i < 4; i++) {
        int idx = tid + i * 256;
        int n = idx >> 5;
        int c = idx & 31;
        int node = base + n;
        float4 xv = make_float4(0.f, 0.f, 0.f, 0.f);
        if (node < NN) xv = ((const float4*)(feat + (size_t)node * DIM))[c];
        ((float4*)&xT[n][0])[c] = xv;
    }

    // Gather-mean into aT.
    {
        int lane = tid & 63, w = tid >> 6;
        int half = lane >> 5;   // edge parity for this half-wave
        int l32 = lane & 31;    // float4 chunk within the 512B row
        for (int i = 0; i < 8; i++) {
            int n = w * 8 + i;
            int node = base + n;
            int beg = 0, end = 0;
            if (node < NN) { beg = rowptr[node]; end = rowptr[node + 1]; }
            int deg = end - beg;
            float4 a0 = make_float4(0.f, 0.f, 0.f, 0.f);
            float4 a1 = a0;
            int e = beg + half;
            for (; e + 2 < end; e += 4) {
                int s0 = col[e];
                int s1 = col[e + 2];
                float4 v0 = ((const float4*)(feat + (size_t)s0 * DIM))[l32];
                float4 v1 = ((const float4*)(feat + (size_t)s1 * DIM))[l32];
                a0.x += v0.x; a0.y += v0.y; a0.z += v0.z; a0.w += v0.w;
                a1.x += v1.x; a1.y += v1.y; a1.z += v1.z; a1.w += v1.w;
            }
            if (e < end) {
                int s0 = col[e];
                float4 v0 = ((const float4*)(feat + (size_t)s0 * DIM))[l32];
                a0.x += v0.x; a0.y += v0.y; a0.z += v0.z; a0.w += v0.w;
            }
            a0.x += a1.x; a0.y += a1.y; a0.z += a1.z; a0.w += a1.w;
            // combine the two edge-parity halves
            a0.x += __shfl_xor(a0.x, 32, 64);
            a0.y += __shfl_xor(a0.y, 32, 64);
            a0.z += __shfl_xor(a0.z, 32, 64);
            a0.w += __shfl_xor(a0.w, 32, 64);
            float di = 1.0f / fmaxf((float)deg, 1.0f);
            if (half == 0) {
                AT4(n)[l32] = make_float4(a0.x * di, a0.y * di, a0.z * di, a0.w * di);
            }
        }
    }
    __syncthreads();

    int j = tid & 127;
    int jh = tid >> 7;
    float acc[16];
    #pragma unroll
    for (int i = 0; i < 16; i++) acc[i] = 0.f;

    for (int k = 0; k < DIM; k += 4) {
        float wl0 = Wl[(k + 0) * DIM + j];
        float wl1 = Wl[(k + 1) * DIM + j];
        float wl2 = Wl[(k + 2) * DIM + j];
        float wl3 = Wl[(k + 3) * DIM + j];
        float wr0 = Wr[(k + 0) * DIM + j];
        float wr1 = Wr[(k + 1) * DIM + j];
        float wr2 = Wr[(k + 2) * DIM + j];
        float wr3 = Wr[(k + 3) * DIM + j];
        #pragma unroll
        for (int i = 0; i < 16; i++) {
            int n = jh * 16 + i;
            float4 a4 = AT4(n)[k >> 2];
            float4 x4 = *(const float4*)&xT[n][k];
            acc[i] += a4.x * wl0 + a4.y * wl1 + a4.z * wl2 + a4.w * wl3
                    + x4.x * wr0 + x4.y * wr1 + x4.z * wr2 + x4.w * wr3;
        }
    }
    __syncthreads();   // all aT reads done before oT overlays it

    float bj = bl[j];
    #pragma unroll
    for (int i = 0; i < 16; i++) {
        int n = jh * 16 + i;
        OT(n, j) = acc[i] + bj;
    }
    __syncthreads();

    // LayerNorm stats: 8 threads per node.
    {
        int n = tid >> 3, l = tid & 7;
        float s = 0.f, s2 = 0.f;
        #pragma unroll
        for (int kk = 0; kk < 16; kk++) {
            float v = OT(n, l * 16 + kk);
            s += v;
            s2 += v * v;
        }
        #pragma unroll
        for (int off = 4; off; off >>= 1) {
            s  += __shfl_down(s, off, 8);
            s2 += __shfl_down(s2, off, 8);
        }
        if (l == 0) {
            float mu = s * (1.0f / DIM);
            float var = s2 * (1.0f / DIM) - mu * mu;
            mu_s[n] = mu;
            ri_s[n] = rsqrtf(fmaxf(var, 0.f) + EPSV);
        }
    }
    __syncthreads();

    if (!DO_HEAD) {
        #pragma unroll
        for (int i = 0; i < 16; i++) {
            int idx = tid + i * 256;
            int n = idx >> 7;
            int k = idx & 127;
            int node = base + n;
            if (node < NN) {
                float v = (OT(n, k) - mu_s[n]) * ri_s[n] * g[k] + beta[k];
                out[(size_t)node * DIM + k] = fmaxf(v, 0.f);
            }
        }
    } else {
        float vals[16];
        #pragma unroll
        for (int i = 0; i < 16; i++) {
            int idx = tid + i * 256;
            int n = idx >> 7;
            int k = idx & 127;
            float v = (OT(n, k) - mu_s[n]) * ri_s[n] * g[k] + beta[k];
            vals[i] = fmaxf(v, 0.f);
        }
        __syncthreads();
        #pragma unroll
        for (int i = 0; i < 16; i++) {
            int idx = tid + i * 256;
            int n = idx >> 7;
            int k = idx & 127;
            OT(n, k) = vals[i];
        }
        __syncthreads();
        if (tid < 128) {
            int n = tid >> 2, o = tid & 3;
            int node = base + n;
            if (node < NN) {
                float s = bh[o];
                for (int k = 0; k < DIM; k++) s += OT(n, k) * Wh[k * OUTD + o];
                out[(size_t)node * OUTD + o] = s;
            }
        }
    }
    #undef AT4
    #undef OT
}

extern "C" void kernel_launch(void* const* d_in, const int* in_sizes, int n_in,
                              void* d_out, int out_size, void* d_ws, size_t ws_size,
                              hipStream_t stream)
{
    const float* x    = (const float*)d_in[0];
    const int*   ei   = (const int*)d_in[1];   // [2, E] int32
    const float* Wl0  = (const float*)d_in[2];
    const float* bl0  = (const float*)d_in[3];
    const float* Wr0  = (const float*)d_in[4];
    const float* Wl1  = (const float*)d_in[5];
    const float* bl1  = (const float*)d_in[6];
    const float* Wr1  = (const float*)d_in[7];
    const float* g0   = (const float*)d_in[8];
    const float* be0  = (const float*)d_in[9];
    const float* g1   = (const float*)d_in[10];
    const float* be1  = (const float*)d_in[11];
    const float* Wh   = (const float*)d_in[12];
    const float* bh   = (const float*)d_in[13];
    float* out = (float*)d_out;

    const int* srcI = ei;
    const int* dstI = ei + EE;

    // Workspace: h [N*128 f32] | rowptr [N+1] | cnt [N] | col [E]
    float* h      = (float*)d_ws;
    int*   rowptr = (int*)((char*)d_ws + (size_t)NN * DIM * sizeof(float));
    int*   cnt    = rowptr + (NN + 1);
    int*   col    = cnt + NN;

    hipMemsetAsync(cnt, 0, NN * sizeof(int), stream);
    hist_kernel<<<(EE + 255) / 256, 256, 0, stream>>>(dstI, cnt);
    scan_kernel<<<1, 1024, 0, stream>>>(cnt, rowptr);
    hipMemsetAsync(cnt, 0, NN * sizeof(int), stream);
    fill_kernel<<<(EE + 255) / 256, 256, 0, stream>>>(srcI, dstI, rowptr, cnt, col);

    const int gemm_blocks = (NN + 31) / 32;
    sage_fused_kernel<0><<<gemm_blocks, 256, 0, stream>>>(
        x, rowptr, col, Wl0, bl0, Wr0, g0, be0, nullptr, nullptr, h);
    sage_fused_kernel<1><<<gemm_blocks, 256, 0, stream>>>(
        h, rowptr, col, Wl1, bl1, Wr1, g1, be1, Wh, bh, out);
}

// Round 4
// 307.747 us; speedup vs baseline: 9.8713x; 1.6756x over previous
//
#include <hip/hip_runtime.h>

#define NN 50000
#define EE 800000
#define DIM 128
#define KK 256          // concat K: [agg(128) | self(128)]
#define OUTD 4
#define EPSV 1e-5f
#define OTS 132         // oT row stride (floats)

using short8v = __attribute__((ext_vector_type(8))) short;   // 8 bf16
using f32x4v  = __attribute__((ext_vector_type(4))) float;

__device__ __forceinline__ unsigned short f2bf(float f) {
    union { float f; unsigned u; } x; x.f = f;
    unsigned r = x.u + 0x7FFF + ((x.u >> 16) & 1);   // RNE
    return (unsigned short)(r >> 16);
}
__device__ __forceinline__ float bf2f(unsigned short u) {
    union { unsigned u; float f; } x; x.u = ((unsigned)u) << 16;
    return x.f;
}

// ---------------------------------------------------------------------------
// x (f32) -> xb (bf16)
// ---------------------------------------------------------------------------
__global__ __launch_bounds__(256) void xprep_kernel(
    const float* __restrict__ x, ushort* __restrict__ xb)
{
    int i = blockIdx.x * 256 + threadIdx.x;
    if (i < NN * DIM / 4) {
        float4 v = ((const float4*)x)[i];
        ushort4 o;
        o.x = f2bf(v.x); o.y = f2bf(v.y); o.z = f2bf(v.z); o.w = f2bf(v.w);
        ((ushort4*)xb)[i] = o;
    }
}

// ---------------------------------------------------------------------------
// Weights -> Wt bf16 [128 j][256 k] (k<128: Wl[k][j], k>=128: Wr[k-128][j])
// ---------------------------------------------------------------------------
__global__ __launch_bounds__(256) void wprep_kernel(
    const float* __restrict__ Wl0, const float* __restrict__ Wr0,
    const float* __restrict__ Wl1, const float* __restrict__ Wr1,
    ushort* __restrict__ Wt0, ushort* __restrict__ Wt1)
{
    int j = blockIdx.x, k = threadIdx.x;
    const float* Wl = blockIdx.y ? Wl1 : Wl0;
    const float* Wr = blockIdx.y ? Wr1 : Wr0;
    ushort* Wt = blockIdx.y ? Wt1 : Wt0;
    float v = (k < 128) ? Wl[k * DIM + j] : Wr[(k - 128) * DIM + j];
    Wt[j * KK + k] = f2bf(v);
}

// ---------------------------------------------------------------------------
// CSR build
// ---------------------------------------------------------------------------
__global__ __launch_bounds__(256) void hist_kernel(
    const int* __restrict__ dst, int* __restrict__ cnt)
{
    int e = blockIdx.x * 256 + threadIdx.x;
    if (e < EE) atomicAdd(&cnt[dst[e]], 1);
}

__global__ __launch_bounds__(1024) void scan_kernel(
    const int* __restrict__ cnt, int* __restrict__ rowptr)
{
    __shared__ int wsum[16];
    __shared__ int carry_s;
    int tid = threadIdx.x, lane = tid & 63, wid = tid >> 6;
    if (tid == 0) carry_s = 0;
    __syncthreads();
    const int NV = NN / 4;   // 12500 int4 units
    for (int base = 0; base < NV; base += 1024) {
        int idx = base + tid;
        int4 v = make_int4(0, 0, 0, 0);
        if (idx < NV) v = ((const int4*)cnt)[idx];
        int t = v.x + v.y + v.z + v.w;
        int s = t;
        #pragma unroll
        for (int off = 1; off < 64; off <<= 1) {
            int u = __shfl_up(s, off, 64);
            if (lane >= off) s += u;
        }
        if (lane == 63) wsum[wid] = s;
        __syncthreads();
        if (tid < 16) {
            int wv = wsum[tid];
            #pragma unroll
            for (int off = 1; off < 16; off <<= 1) {
                int u = __shfl_up(wv, off, 16);
                if (tid >= off) wv += u;
            }
            wsum[tid] = wv;
        }
        __syncthreads();
        if (idx < NV) {
            int excl = carry_s + (wid ? wsum[wid - 1] : 0) + (s - t);
            int p = idx * 4;
            rowptr[p]     = excl;
            rowptr[p + 1] = excl + v.x;
            rowptr[p + 2] = excl + v.x + v.y;
            rowptr[p + 3] = excl + v.x + v.y + v.z;
        }
        __syncthreads();
        if (tid == 0) carry_s += wsum[15];
        __syncthreads();
    }
    if (tid == 0) rowptr[NN] = carry_s;
}

__global__ __launch_bounds__(256) void fill_kernel(
    const int* __restrict__ src, const int* __restrict__ dst,
    const int* __restrict__ rowptr, int* __restrict__ cursor,
    int* __restrict__ col)
{
    int e = blockIdx.x * 256 + threadIdx.x;
    if (e >= EE) return;
    int d = dst[e];
    int pos = rowptr[d] + atomicAdd(&cursor[d], 1);
    col[pos] = src[e];
}

// ---------------------------------------------------------------------------
// Fused layer (bf16 features end-to-end, MFMA GEMM):
//   featB LDS [32 nodes][256 k] bf16, XOR-swizzled (kb ^= (n&7)<<4).
//   k<128 = gather-mean(neighbors), k>=128 = self feature.
//   C = featB @ Wt^T via mfma_f32_16x16x32_bf16; +bl; LN(f32); ReLU.
//   DO_HEAD=0: out = h bf16 [N][128].  DO_HEAD=1: out = f32 [N][4] head.
// ---------------------------------------------------------------------------
template <int DO_HEAD>
__global__ __launch_bounds__(256) void sage_fused_kernel(
    const ushort* __restrict__ featG,     // bf16 [N][128]
    const int* __restrict__ rowptr, const int* __restrict__ col,
    const ushort* __restrict__ WtB,       // bf16 [128 j][256 k]
    const float* __restrict__ bl,
    const float* __restrict__ g, const float* __restrict__ beta,
    const float* __restrict__ Wh, const float* __restrict__ bh,
    void* __restrict__ outp)
{
    __shared__ __align__(16) char smem[32 * OTS * 4];   // 16.9 KB
    __shared__ float mu_s[32], ri_s[32];
    ushort* featB = (ushort*)smem;            // [32][256] bf16, swizzled
    float*  oT    = (float*)smem;             // overlays featB after MFMA
    #define OT(n, k) oT[(n) * OTS + (k)]

    int tid = threadIdx.x;
    int base = blockIdx.x * 32;
    int lane = tid & 63, w = tid >> 6;

    // ---- self-feature part: featB[n][128..256) ----
    #pragma unroll
    for (int i = 0; i < 4; i++) {
        int idx = tid + i * 256;
        int n = idx >> 5, c = idx & 31;
        int node = base + n;
        ushort4 xv = make_ushort4(0, 0, 0, 0);
        if (node < NN) xv = *(const ushort4*)(featG + (size_t)node * DIM + c * 4);
        int kb = (256 + c * 8) ^ ((n & 7) << 4);
        *(ushort4*)(featB + n * KK + (kb >> 1)) = xv;
    }

    // ---- gather-mean: featB[n][0..128) ----
    {
        int half = lane >> 5, l32 = lane & 31;
        for (int i = 0; i < 8; i++) {
            int n = w * 8 + i;
            int node = base + n;
            int beg = 0, end = 0;
            if (node < NN) { beg = rowptr[node]; end = rowptr[node + 1]; }
            int deg = end - beg;
            float ax = 0.f, ay = 0.f, az = 0.f, aw = 0.f;
            float bx = 0.f, by = 0.f, bz = 0.f, bw = 0.f;
            int e = beg + half;
            for (; e + 2 < end; e += 4) {
                int s0 = col[e], s1 = col[e + 2];
                ushort4 v0 = *(const ushort4*)(featG + (size_t)s0 * DIM + l32 * 4);
                ushort4 v1 = *(const ushort4*)(featG + (size_t)s1 * DIM + l32 * 4);
                ax += bf2f(v0.x); ay += bf2f(v0.y); az += bf2f(v0.z); aw += bf2f(v0.w);
                bx += bf2f(v1.x); by += bf2f(v1.y); bz += bf2f(v1.z); bw += bf2f(v1.w);
            }
            if (e < end) {
                ushort4 v0 = *(const ushort4*)(featG + (size_t)col[e] * DIM + l32 * 4);
                ax += bf2f(v0.x); ay += bf2f(v0.y); az += bf2f(v0.z); aw += bf2f(v0.w);
            }
            ax += bx; ay += by; az += bz; aw += bw;
            ax += __shfl_xor(ax, 32, 64);
            ay += __shfl_xor(ay, 32, 64);
            az += __shfl_xor(az, 32, 64);
            aw += __shfl_xor(aw, 32, 64);
            if (half == 0) {
                float di = 1.0f / fmaxf((float)deg, 1.0f);
                ushort4 o;
                o.x = f2bf(ax * di); o.y = f2bf(ay * di);
                o.z = f2bf(az * di); o.w = f2bf(aw * di);
                int kb = (l32 * 8) ^ ((n & 7) << 4);
                *(ushort4*)(featB + n * KK + (kb >> 1)) = o;
            }
        }
    }
    __syncthreads();

    // ---- MFMA: C[32][128] = featB[32][256] x W[256][128] ----
    int l15 = lane & 15, q = lane >> 4;
    f32x4v acc00 = {}, acc01 = {}, acc10 = {}, acc11 = {};
    const ushort* wbase = WtB + (size_t)(w * 32) * KK;
    int n0 = l15, n1 = 16 + l15;
    int sw = (l15 & 7) << 4;                  // same for n0 and n1
    #pragma unroll
    for (int ks = 0; ks < 8; ks++) {
        int kbA = ks * 64 + q * 16;
        short8v a0 = *(const short8v*)(featB + n0 * KK + (((kbA) ^ sw) >> 1));
        short8v a1 = *(const short8v*)(featB + n1 * KK + (((kbA) ^ sw) >> 1));
        int koff = ks * 32 + q * 8;
        short8v b0 = *(const short8v*)(wbase + (size_t)l15 * KK + koff);
        short8v b1 = *(const short8v*)(wbase + (size_t)(16 + l15) * KK + koff);
        acc00 = __builtin_amdgcn_mfma_f32_16x16x32_bf16(a0, b0, acc00, 0, 0, 0);
        acc01 = __builtin_amdgcn_mfma_f32_16x16x32_bf16(a0, b1, acc01, 0, 0, 0);
        acc10 = __builtin_amdgcn_mfma_f32_16x16x32_bf16(a1, b0, acc10, 0, 0, 0);
        acc11 = __builtin_amdgcn_mfma_f32_16x16x32_bf16(a1, b1, acc11, 0, 0, 0);
    }
    __syncthreads();   // all featB reads done before oT overlays it

    // D layout: col = lane&15, row = (lane>>4)*4 + r  [guide §3, m89-verified]
    {
        int c0 = w * 32 + l15, c1 = c0 + 16;
        float bl0v = bl[c0], bl1v = bl[c1];
        #pragma unroll
        for (int r = 0; r < 4; r++) {
            int r0 = q * 4 + r, r1 = 16 + q * 4 + r;
            OT(r0, c0) = acc00[r] + bl0v;
            OT(r0, c1) = acc01[r] + bl1v;
            OT(r1, c0) = acc10[r] + bl0v;
            OT(r1, c1) = acc11[r] + bl1v;
        }
    }
    __syncthreads();

    // ---- LayerNorm stats (f32): 8 threads per node ----
    {
        int n = tid >> 3, l = tid & 7;
        float s = 0.f, s2 = 0.f;
        #pragma unroll
        for (int kk = 0; kk < 16; kk++) {
            float v = OT(n, l * 16 + kk);
            s += v; s2 += v * v;
        }
        #pragma unroll
        for (int off = 4; off; off >>= 1) {
            s  += __shfl_down(s, off, 8);
            s2 += __shfl_down(s2, off, 8);
        }
        if (l == 0) {
            float mu = s * (1.0f / DIM);
            float var = s2 * (1.0f / DIM) - mu * mu;
            mu_s[n] = mu;
            ri_s[n] = rsqrtf(fmaxf(var, 0.f) + EPSV);
        }
    }
    __syncthreads();

    if (!DO_HEAD) {
        ushort* hout = (ushort*)outp;
        #pragma unroll
        for (int i = 0; i < 16; i++) {
            int idx = tid + i * 256;
            int n = idx >> 7, k = idx & 127;
            int node = base + n;
            if (node < NN) {
                float v = (OT(n, k) - mu_s[n]) * ri_s[n] * g[k] + beta[k];
                hout[(size_t)node * DIM + k] = f2bf(fmaxf(v, 0.f));
            }
        }
    } else {
        float* fout = (float*)outp;
        float vals[16];
        #pragma unroll
        for (int i = 0; i < 16; i++) {
            int idx = tid + i * 256;
            int n = idx >> 7, k = idx & 127;
            float v = (OT(n, k) - mu_s[n]) * ri_s[n] * g[k] + beta[k];
            vals[i] = fmaxf(v, 0.f);
        }
        __syncthreads();
        #pragma unroll
        for (int i = 0; i < 16; i++) {
            int idx = tid + i * 256;
            int n = idx >> 7, k = idx & 127;
            OT(n, k) = vals[i];
        }
        __syncthreads();
        if (tid < 128) {
            int n = tid >> 2, o = tid & 3;
            int node = base + n;
            if (node < NN) {
                float s = bh[o];
                for (int k = 0; k < DIM; k++) s += OT(n, k) * Wh[k * OUTD + o];
                fout[(size_t)node * OUTD + o] = s;
            }
        }
    }
    #undef OT
}

extern "C" void kernel_launch(void* const* d_in, const int* in_sizes, int n_in,
                              void* d_out, int out_size, void* d_ws, size_t ws_size,
                              hipStream_t stream)
{
    const float* x    = (const float*)d_in[0];
    const int*   ei   = (const int*)d_in[1];   // [2, E] int32
    const float* Wl0  = (const float*)d_in[2];
    const float* bl0  = (const float*)d_in[3];
    const float* Wr0  = (const float*)d_in[4];
    const float* Wl1  = (const float*)d_in[5];
    const float* bl1  = (const float*)d_in[6];
    const float* Wr1  = (const float*)d_in[7];
    const float* g0   = (const float*)d_in[8];
    const float* be0  = (const float*)d_in[9];
    const float* g1   = (const float*)d_in[10];
    const float* be1  = (const float*)d_in[11];
    const float* Wh   = (const float*)d_in[12];
    const float* bh   = (const float*)d_in[13];
    float* out = (float*)d_out;

    const int* srcI = ei;
    const int* dstI = ei + EE;

    // ws layout (16B-aligned): xb | h | Wt0 | Wt1 | rowptr | cnt | cursor | col
    char* p = (char*)d_ws;
    ushort* xb     = (ushort*)p;                       p += (size_t)NN * DIM * 2;   // 12.8 MB
    ushort* h      = (ushort*)p;                       p += (size_t)NN * DIM * 2;   // 12.8 MB
    ushort* Wt0    = (ushort*)p;                       p += DIM * KK * 2;           // 64 KB
    ushort* Wt1    = (ushort*)p;                       p += DIM * KK * 2;           // 64 KB
    int*    rowptr = (int*)p;                          p += 50004 * 4;              // N+1, padded
    int*    cnt    = (int*)p;                          p += NN * 4;
    int*    cursor = (int*)p;                          p += NN * 4;
    int*    col    = (int*)p;

    // prep
    xprep_kernel<<<(NN * DIM / 4 + 255) / 256, 256, 0, stream>>>(x, xb);
    wprep_kernel<<<dim3(128, 2), 256, 0, stream>>>(Wl0, Wr0, Wl1, Wr1, Wt0, Wt1);

    // CSR build
    hipMemsetAsync(cnt, 0, 2 * NN * sizeof(int), stream);   // cnt + cursor
    hist_kernel<<<(EE + 255) / 256, 256, 0, stream>>>(dstI, cnt);
    scan_kernel<<<1, 1024, 0, stream>>>(cnt, rowptr);
    fill_kernel<<<(EE + 255) / 256, 256, 0, stream>>>(srcI, dstI, rowptr, cursor, col);

    // fused layers
    const int blocks = (NN + 31) / 32;
    sage_fused_kernel<0><<<blocks, 256, 0, stream>>>(
        xb, rowptr, col, Wt0, bl0, g0, be0, nullptr, nullptr, (void*)h);
    sage_fused_kernel<1><<<blocks, 256, 0, stream>>>(
        h, rowptr, col, Wt1, bl1, g1, be1, Wh, bh, (void*)out);
}